// Round 1
// baseline (414.927 us; speedup 1.0000x reference)
//
#include <hip/hip_runtime.h>

// out[i] = x[i]*x[i] + 2*x[i], fp32, n = 8192*8192 = 67,108,864 (divisible by 4).
// Pure streaming kernel: float4 loads/stores, one vec4 per thread.

__global__ void __launch_bounds__(256) sq_plus_2x_kernel(
    const float4* __restrict__ x, float4* __restrict__ out, unsigned int n4) {
    unsigned int i = blockIdx.x * 256u + threadIdx.x;
    if (i < n4) {
        float4 v = x[i];
        float4 r;
        r.x = v.x * v.x + 2.0f * v.x;
        r.y = v.y * v.y + 2.0f * v.y;
        r.z = v.z * v.z + 2.0f * v.z;
        r.w = v.w * v.w + 2.0f * v.w;
        out[i] = r;
    }
}

extern "C" void kernel_launch(void* const* d_in, const int* in_sizes, int n_in,
                              void* d_out, int out_size, void* d_ws, size_t ws_size,
                              hipStream_t stream) {
    const float* x = (const float*)d_in[0];
    float* out = (float*)d_out;
    unsigned int n = (unsigned int)in_sizes[0];   // 67,108,864
    unsigned int n4 = n / 4;                      // 16,777,216 (n is a multiple of 4)
    unsigned int blocks = (n4 + 255u) / 256u;     // 65,536
    sq_plus_2x_kernel<<<blocks, 256, 0, stream>>>(
        (const float4*)x, (float4*)out, n4);
}